// Round 2
// baseline (1886.310 us; speedup 1.0000x reference)
//
#include <hip/hip_runtime.h>
#include <hip/hip_bf16.h>
#include <cstdint>

typedef unsigned short u16;
typedef __attribute__((ext_vector_type(8))) u16 u16x8;
typedef __attribute__((ext_vector_type(8))) short s16x8;   // bf16 MFMA frag (guide §3)
typedef __attribute__((ext_vector_type(4))) float f32x4;

#define AS1(p) ((const __attribute__((address_space(1))) void*)(p))
#define AS3(p) ((__attribute__((address_space(3))) void*)(p))

__device__ __forceinline__ u16 f2bf(float f){
  union{float f; uint32_t i;} x; x.f = f;
  uint32_t r = x.i + 0x7fff + ((x.i>>16)&1);
  return (u16)(r>>16);
}

// ------------- weight transpose: in f32 [K][N] -> out bf16 [N][K] ------------
__global__ void transpose_f32_bf16(const float* __restrict__ in, u16* __restrict__ out,
                                   int K, int N){
  __shared__ u16 tile[32][33];
  const int tid = threadIdx.x;
  const int bx = blockIdx.x;   // over N
  const int by = blockIdx.y;   // over K
  const int xl = tid & 31, yl = tid >> 5;  // 32 x 8
  #pragma unroll
  for (int r = 0; r < 4; ++r){
    int y = by*32 + yl + r*8;
    tile[yl + r*8][xl] = f2bf(in[(size_t)y*N + bx*32 + xl]);
  }
  __syncthreads();
  #pragma unroll
  for (int r = 0; r < 4; ++r){
    int oy = bx*32 + yl + r*8;           // N index
    int ox = by*32 + xl;                 // K index
    out[(size_t)oy*K + ox] = tile[xl][yl + r*8];
  }
}

// -------- bias1[t][h] = b1[h] + cH_t*W1[2048,h] + cS_t*W1[2049,h] (f32) ------
__global__ void build_bias1(const float* __restrict__ W1, const float* __restrict__ b1,
                            const int* __restrict__ head, const int* __restrict__ tail,
                            const int* __restrict__ sign, float* __restrict__ bias1){
  int idx = blockIdx.x*256 + threadIdx.x;   // [0, 8*4096)
  int t = idx >> 12, h = idx & 4095;
  float cH = 0.f, cS = 0.f;
  #pragma unroll
  for (int e = 0; e < 16; ++e){
    float s = 1.f - 2.f*(float)sign[e];
    if (head[e] == t){ cH += 1.f; cS += s; }
    if (tail[e] == t){ cH -= 1.f; cS += s; }
  }
  bias1[idx] = b1[h] + cH*W1[(size_t)2048*4096 + h] + cS*W1[(size_t)2049*4096 + h];
}

// --- X1[r,0:1024] = bf16(deg_t*term[r]); X1[r,1024:2048] = bf16(sum pred) ----
__global__ void build_x1(const float* __restrict__ term, const float* __restrict__ pred,
                         const int* __restrict__ head, const int* __restrict__ tail,
                         u16* __restrict__ X1, int r0){
  int idx = blockIdx.x*256 + threadIdx.x;   // one block per row
  int lr = idx >> 8;
  int c8 = (idx & 255) * 8;
  int grow = r0 + lr;
  int t = grow >> 12;
  int b = grow & 4095;
  float v[8];
  if (c8 < 1024){
    int deg = 0;
    #pragma unroll
    for (int e = 0; e < 16; ++e) deg += (head[e]==t) + (tail[e]==t);
    float d = (float)deg;
    const float4* p = (const float4*)(term + (size_t)grow*1024 + c8);
    float4 lo = p[0], hi = p[1];
    v[0]=d*lo.x; v[1]=d*lo.y; v[2]=d*lo.z; v[3]=d*lo.w;
    v[4]=d*hi.x; v[5]=d*hi.y; v[6]=d*hi.z; v[7]=d*hi.w;
  } else {
    int f = c8 - 1024;
    #pragma unroll
    for (int j = 0; j < 8; ++j) v[j] = 0.f;
    #pragma unroll
    for (int e = 0; e < 16; ++e){
      int w = (head[e]==t) + (tail[e]==t);
      if (w){
        const float4* p = (const float4*)(pred + ((size_t)e<<22) + ((size_t)b<<10) + f);
        float4 lo = p[0], hi = p[1];
        float fw = (float)w;
        v[0]+=fw*lo.x; v[1]+=fw*lo.y; v[2]+=fw*lo.z; v[3]+=fw*lo.w;
        v[4]+=fw*hi.x; v[5]+=fw*hi.y; v[6]+=fw*hi.z; v[7]+=fw*hi.w;
      }
    }
  }
  u16x8 o;
  #pragma unroll
  for (int j = 0; j < 8; ++j) o[j] = f2bf(v[j]);
  *(u16x8*)(X1 + (size_t)lr*2048 + c8) = o;
}

// ---------------- GEMM: C[r,n] = epi( sum_k A[r,k] * Bt[n,k] ) ----------------
// A: [Mrows][K] bf16 (chunk-local), Bt: [N][K] bf16.
// 128x128 tile, BK=32, 4 waves 2x2, 4x4 16x16x32 MFMA frags/wave.
// LDS [128][32] bf16, XOR-swizzled 16B groups (slot gs holds global gs^(row&3));
// staged via global_load_lds with pre-swizzled global source (rule #21).
// MODE 0: +bias_mat[t][n], relu -> bf16 C
// MODE 1: +bias_vec[n] + 0.1*resid[grow*1024+n] -> bf16 C
// MODE 2: +bias_vec[n], relu -> bf16 C
// MODE 3: +bias_vec[n] -> f32 C (d_out)
template<int MODE>
__launch_bounds__(256, 2)
__global__ void gemm_bt(const u16* __restrict__ A, const u16* __restrict__ Bt,
                        void* __restrict__ Cv, int N, int K, int r0,
                        const float* __restrict__ bias_mat,
                        const float* __restrict__ bias_vec,
                        const float* __restrict__ resid){
  __shared__ u16 As[128*32];
  __shared__ u16 Bs[128*32];
  const int tid  = threadIdx.x;
  const int lane = tid & 63;
  const int wid  = tid >> 6;
  const int wr = wid >> 1, wc = wid & 1;
  const int row0 = blockIdx.y * 128;
  const int col0 = blockIdx.x * 128;

  // staging: 512 16B-chunks per tile, 2 per thread. chunk c -> row c>>2, slot c&3
  const int c0 = tid, c1 = tid + 256;
  const int ar0 = c0 >> 2, ag0 = (c0 & 3) ^ (ar0 & 3);
  const int ar1 = c1 >> 2, ag1 = (c1 & 3) ^ (ar1 & 3);
  const u16* aSrc0 = A  + (size_t)(row0 + ar0)*K + ag0*8;
  const u16* aSrc1 = A  + (size_t)(row0 + ar1)*K + ag1*8;
  const u16* bSrc0 = Bt + (size_t)(col0 + ar0)*K + ag0*8;
  const u16* bSrc1 = Bt + (size_t)(col0 + ar1)*K + ag1*8;
  u16* aDst0 = As + c0*8; u16* aDst1 = As + c1*8;
  u16* bDst0 = Bs + c0*8; u16* bDst1 = Bs + c1*8;

  f32x4 acc[4][4];
  #pragma unroll
  for (int i = 0; i < 4; ++i)
    #pragma unroll
    for (int j = 0; j < 4; ++j) acc[i][j] = (f32x4){0.f,0.f,0.f,0.f};

  const int frow = lane & 15;
  const int fgrp = lane >> 4;
  int a_off[4], b_off[4];
  #pragma unroll
  for (int f = 0; f < 4; ++f){
    int ra = wr*64 + f*16 + frow;
    a_off[f] = ra*64 + ((fgrp ^ (ra & 3)) << 4);
    int rb = wc*64 + f*16 + frow;
    b_off[f] = rb*64 + ((fgrp ^ (rb & 3)) << 4);
  }

  const int nk = K >> 5;
  for (int kt = 0; kt < nk; ++kt){
    __syncthreads();
    __builtin_amdgcn_global_load_lds(AS1(aSrc0), AS3(aDst0), 16, 0, 0);
    __builtin_amdgcn_global_load_lds(AS1(aSrc1), AS3(aDst1), 16, 0, 0);
    __builtin_amdgcn_global_load_lds(AS1(bSrc0), AS3(bDst0), 16, 0, 0);
    __builtin_amdgcn_global_load_lds(AS1(bSrc1), AS3(bDst1), 16, 0, 0);
    aSrc0 += 32; aSrc1 += 32; bSrc0 += 32; bSrc1 += 32;
    __syncthreads();
    s16x8 af[4], bfr[4];
    #pragma unroll
    for (int f = 0; f < 4; ++f) af[f]  = *(const s16x8*)((const char*)As + a_off[f]);
    #pragma unroll
    for (int f = 0; f < 4; ++f) bfr[f] = *(const s16x8*)((const char*)Bs + b_off[f]);
    #pragma unroll
    for (int i = 0; i < 4; ++i)
      #pragma unroll
      for (int j = 0; j < 4; ++j)
        acc[i][j] = __builtin_amdgcn_mfma_f32_16x16x32_bf16(af[i], bfr[j], acc[i][j], 0, 0, 0);
  }

  // epilogue: C/D layout col=lane&15, row=(lane>>4)*4+reg (m89-verified)
  #pragma unroll
  for (int i = 0; i < 4; ++i){
    #pragma unroll
    for (int j = 0; j < 4; ++j){
      #pragma unroll
      for (int r = 0; r < 4; ++r){
        int lrow = row0 + wr*64 + i*16 + fgrp*4 + r;
        int col  = col0 + wc*64 + j*16 + frow;
        float v = acc[i][j][r];
        if (MODE == 0){
          int grow = r0 + lrow;
          v += bias_mat[(size_t)(grow >> 12)*N + col];
          v = fmaxf(v, 0.f);
          ((u16*)Cv)[(size_t)lrow*N + col] = f2bf(v);
        } else if (MODE == 1){
          int grow = r0 + lrow;
          v += bias_vec[col] + 0.1f*resid[(size_t)grow*1024 + col];
          ((u16*)Cv)[(size_t)lrow*N + col] = f2bf(v);
        } else if (MODE == 2){
          v += bias_vec[col];
          v = fmaxf(v, 0.f);
          ((u16*)Cv)[(size_t)lrow*N + col] = f2bf(v);
        } else {
          v += bias_vec[col];
          ((float*)Cv)[(size_t)lrow*N + col] = v;
        }
      }
    }
  }
}

extern "C" void kernel_launch(void* const* d_in, const int* in_sizes, int n_in,
                              void* d_out, int out_size, void* d_ws, size_t ws_size,
                              hipStream_t stream){
  const float* term = (const float*)d_in[0];
  const float* pred = (const float*)d_in[1];
  const float* W1   = (const float*)d_in[2];
  const float* b1   = (const float*)d_in[3];
  const float* W2   = (const float*)d_in[4];
  const float* b2   = (const float*)d_in[5];
  const float* M1   = (const float*)d_in[6];
  const float* mb1  = (const float*)d_in[7];
  const float* M2   = (const float*)d_in[8];
  const float* mb2  = (const float*)d_in[9];
  const int* head = (const int*)d_in[10];
  const int* tail = (const int*)d_in[11];
  const int* sign = (const int*)d_in[12];
  float* out = (float*)d_out;

  char* ws = (char*)d_ws;
  u16* W1T = (u16*)ws;  ws += (size_t)4096*2048*2;
  u16* W2T = (u16*)ws;  ws += (size_t)1024*4096*2;
  u16* M1T = (u16*)ws;  ws += (size_t)4096*1024*2;
  u16* M2T = (u16*)ws;  ws += (size_t)1024*4096*2;
  float* bias1 = (float*)ws; ws += (size_t)8*4096*4;
  size_t used = (size_t)(ws - (char*)d_ws);

  int R = 32768;  // rows per chunk; shrink if workspace is small
  while (R > 128 && used + (size_t)R*12288 > ws_size) R >>= 1;
  u16* bufA = (u16*)ws;                          // X1 chunk [R][2048], later x [R][1024]
  u16* bufB = (u16*)(ws + (size_t)R*2048*2);     // h1 chunk [R][4096], later h2

  transpose_f32_bf16<<<dim3(4096/32, 2048/32), 256, 0, stream>>>(W1, W1T, 2048, 4096);
  transpose_f32_bf16<<<dim3(1024/32, 4096/32), 256, 0, stream>>>(W2, W2T, 4096, 1024);
  transpose_f32_bf16<<<dim3(4096/32, 1024/32), 256, 0, stream>>>(M1, M1T, 1024, 4096);
  transpose_f32_bf16<<<dim3(1024/32, 4096/32), 256, 0, stream>>>(M2, M2T, 4096, 1024);
  build_bias1<<<dim3(8*4096/256), 256, 0, stream>>>(W1, b1, head, tail, sign, bias1);

  for (int r0 = 0; r0 < 32768; r0 += R){
    build_x1<<<dim3(R), 256, 0, stream>>>(term, pred, head, tail, bufA, r0);
    gemm_bt<0><<<dim3(4096/128, R/128), 256, 0, stream>>>(bufA, W1T, bufB, 4096, 2048, r0, bias1, nullptr, nullptr);
    gemm_bt<1><<<dim3(1024/128, R/128), 256, 0, stream>>>(bufB, W2T, bufA, 1024, 4096, r0, nullptr, b2, term);
    gemm_bt<2><<<dim3(4096/128, R/128), 256, 0, stream>>>(bufA, M1T, bufB, 4096, 1024, r0, nullptr, mb1, nullptr);
    gemm_bt<3><<<dim3(1024/128, R/128), 256, 0, stream>>>(bufB, M2T, out + (size_t)r0*1024, 1024, 4096, r0, nullptr, mb2, nullptr);
  }
}

// Round 3
// 1352.164 us; speedup vs baseline: 1.3950x; 1.3950x over previous
//
#include <hip/hip_runtime.h>
#include <hip/hip_bf16.h>
#include <cstdint>

typedef unsigned short u16;
typedef __attribute__((ext_vector_type(8))) u16 u16x8;
typedef __attribute__((ext_vector_type(8))) short s16x8;   // bf16 MFMA frag
typedef __attribute__((ext_vector_type(4))) float f32x4;

#define AS1(p) ((const __attribute__((address_space(1))) void*)(p))
#define AS3(p) ((__attribute__((address_space(3))) void*)(p))

__device__ __forceinline__ u16 f2bf(float f){
  union{float f; uint32_t i;} x; x.f = f;
  uint32_t r = x.i + 0x7fff + ((x.i>>16)&1);
  return (u16)(r>>16);
}

// ------------- weight transpose: in f32 [K][N] -> out bf16 [N][K] ------------
__global__ void transpose_f32_bf16(const float* __restrict__ in, u16* __restrict__ out,
                                   int K, int N){
  __shared__ u16 tile[32][33];
  const int tid = threadIdx.x;
  const int bx = blockIdx.x, by = blockIdx.y;
  const int xl = tid & 31, yl = tid >> 5;
  #pragma unroll
  for (int r = 0; r < 4; ++r){
    int y = by*32 + yl + r*8;
    tile[yl + r*8][xl] = f2bf(in[(size_t)y*N + bx*32 + xl]);
  }
  __syncthreads();
  #pragma unroll
  for (int r = 0; r < 4; ++r){
    int oy = bx*32 + yl + r*8;
    int ox = by*32 + xl;
    out[(size_t)oy*K + ox] = tile[xl][yl + r*8];
  }
}

// -------- bias1[t][h] = b1[h] + cH_t*W1[2048,h] + cS_t*W1[2049,h] (f32) ------
__global__ void build_bias1(const float* __restrict__ W1, const float* __restrict__ b1,
                            const int* __restrict__ head, const int* __restrict__ tail,
                            const int* __restrict__ sign, float* __restrict__ bias1){
  int idx = blockIdx.x*256 + threadIdx.x;
  int t = idx >> 12, h = idx & 4095;
  float cH = 0.f, cS = 0.f;
  #pragma unroll
  for (int e = 0; e < 16; ++e){
    float s = 1.f - 2.f*(float)sign[e];
    if (head[e] == t){ cH += 1.f; cS += s; }
    if (tail[e] == t){ cH -= 1.f; cS += s; }
  }
  bias1[idx] = b1[h] + cH*W1[(size_t)2048*4096 + h] + cS*W1[(size_t)2049*4096 + h];
}

// --- X1[r,0:1024] = bf16(deg_t*term[r]); X1[r,1024:2048] = bf16(sum pred) ----
__global__ void build_x1(const float* __restrict__ term, const float* __restrict__ pred,
                         const int* __restrict__ head, const int* __restrict__ tail,
                         u16* __restrict__ X1, int r0){
  int idx = blockIdx.x*256 + threadIdx.x;
  int lr = idx >> 8;
  int c8 = (idx & 255) * 8;
  int grow = r0 + lr;
  int t = grow >> 12;
  int b = grow & 4095;
  float v[8];
  if (c8 < 1024){
    int deg = 0;
    #pragma unroll
    for (int e = 0; e < 16; ++e) deg += (head[e]==t) + (tail[e]==t);
    float d = (float)deg;
    const float4* p = (const float4*)(term + (size_t)grow*1024 + c8);
    float4 lo = p[0], hi = p[1];
    v[0]=d*lo.x; v[1]=d*lo.y; v[2]=d*lo.z; v[3]=d*lo.w;
    v[4]=d*hi.x; v[5]=d*hi.y; v[6]=d*hi.z; v[7]=d*hi.w;
  } else {
    int f = c8 - 1024;
    #pragma unroll
    for (int j = 0; j < 8; ++j) v[j] = 0.f;
    #pragma unroll
    for (int e = 0; e < 16; ++e){
      int w = (head[e]==t) + (tail[e]==t);
      if (w){
        const float4* p = (const float4*)(pred + ((size_t)e<<22) + ((size_t)b<<10) + f);
        float4 lo = p[0], hi = p[1];
        float fw = (float)w;
        v[0]+=fw*lo.x; v[1]+=fw*lo.y; v[2]+=fw*lo.z; v[3]+=fw*lo.w;
        v[4]+=fw*hi.x; v[5]+=fw*hi.y; v[6]+=fw*hi.z; v[7]+=fw*hi.w;
      }
    }
  }
  u16x8 o;
  #pragma unroll
  for (int j = 0; j < 8; ++j) o[j] = f2bf(v[j]);
  *(u16x8*)(X1 + (size_t)lr*2048 + c8) = o;
}

// =====================  256x256 8-phase GEMM (T1+T2+T3+T4+T5)  ===============
// C[r,n] = epi( sum_k A[r,k] * Bt[n,k] ), A:[M][K] bf16, Bt:[N][K] bf16.
// 512 thr = 8 waves (2Mx4N), per-wave 128x64 out, BK=64, LDS 128KB:
//   A: [slot][half][128 rows][8 chunk-slots of 16B], chunks XOR-swizzled
//   (slot s_g = (q&7)^(row&7)); staged linearly via global_load_lds with
//   pre-swizzled global source (rule #21).
// 8 phases/iter, 2 K-tiles/iter, one half-tile staged per phase,
// vmcnt(6) only at phase 3/7 ends (3 half-tiles in flight, never 0).
#define FENCE() asm volatile("" ::: "memory")
#define BAR()   do{ FENCE(); __builtin_amdgcn_s_barrier(); FENCE(); }while(0)
#define LGKM0() do{ asm volatile("s_waitcnt lgkmcnt(0)" ::: "memory"); \
                    __builtin_amdgcn_sched_barrier(0); }while(0)
#define VM6()   asm volatile("s_waitcnt vmcnt(6)" ::: "memory")

#define STAGE(isB, slot, half, kt) do{ \
    const u16* _s = (isB ? bStage : aStage) + ((half) ? halfStride : (size_t)0) + ((size_t)(kt) << 6); \
    u16* _d = &LDS[(isB ? 32768 : 0) + (slot)*16384 + (half)*8192 + tid*8]; \
    __builtin_amdgcn_global_load_lds(AS1(_s), AS3(_d), 16, 0, 0); \
    __builtin_amdgcn_global_load_lds(AS1(_s + q2s), AS3(_d + 4096), 16, 0, 0); \
  }while(0)

#define LOADA(slot, rh) do{ \
    _Pragma("unroll") \
    for (int ii = 0; ii < 4; ++ii){ \
      af[ii][0] = *(const s16x8*)&LDS[(slot)*16384 + aB + ((rh)*4+ii)*1024 + xv0]; \
      af[ii][1] = *(const s16x8*)&LDS[(slot)*16384 + aB + ((rh)*4+ii)*1024 + xv1]; \
    } }while(0)

#define LOADB(slot) do{ \
    _Pragma("unroll") \
    for (int jj = 0; jj < 4; ++jj){ \
      bfr[jj][0] = *(const s16x8*)&LDS[32768 + (slot)*16384 + bB + jj*1024 + xv0]; \
      bfr[jj][1] = *(const s16x8*)&LDS[32768 + (slot)*16384 + bB + jj*1024 + xv1]; \
    } }while(0)

#define MFMAQ(rh, ch) do{ \
    _Pragma("unroll") \
    for (int ii = 0; ii < 4; ++ii){ \
      _Pragma("unroll") \
      for (int jj = 0; jj < 2; ++jj){ \
        acc[(rh)*4+ii][(ch)*2+jj] = __builtin_amdgcn_mfma_f32_16x16x32_bf16(af[ii][0], bfr[(ch)*2+jj][0], acc[(rh)*4+ii][(ch)*2+jj], 0,0,0); \
        acc[(rh)*4+ii][(ch)*2+jj] = __builtin_amdgcn_mfma_f32_16x16x32_bf16(af[ii][1], bfr[(ch)*2+jj][1], acc[(rh)*4+ii][(ch)*2+jj], 0,0,0); \
      } } }while(0)

template<int MODE>
__launch_bounds__(512, 2)
__global__ void gemm256(const u16* __restrict__ A, const u16* __restrict__ Bt,
                        void* __restrict__ Cv, int N, int K, int r0,
                        const float* __restrict__ bias_mat,
                        const float* __restrict__ bias_vec,
                        const float* __restrict__ resid){
  __shared__ u16 LDS[65536];   // 128 KiB
  const int tid = threadIdx.x;
  const int lane = tid & 63;
  const int wid = tid >> 6;
  const int wr = wid >> 2, wc = wid & 3;
  const int frow = lane & 15, fgrp = lane >> 4;

  // T1: bijective XCD swizzle (nwg here is always a multiple of 8 unless tiny)
  int nwg = gridDim.x * gridDim.y;
  int orig = blockIdx.y * gridDim.x + blockIdx.x;
  int id = orig;
  if ((nwg & 7) == 0){ int cpx = nwg >> 3; id = (orig & 7) * cpx + (orig >> 3); }
  const int bx = id % gridDim.x, by = id / gridDim.x;
  const int row0 = by * 256, col0 = bx * 256;

  // stage source bases (pre-swizzled global source, linear LDS dest)
  const size_t rowK = (size_t)(tid >> 3) * K;
  const int sg8 = (((tid & 7) ^ ((tid >> 3) & 7)) << 3);
  const u16* aStage = A  + (size_t)row0 * K + rowK + sg8;
  const u16* bStage = Bt + (size_t)col0 * K + rowK + sg8;
  const size_t halfStride = (size_t)128 * K;
  const size_t q2s = (size_t)64 * K;

  // fragment read offsets (u16 units), swizzled
  const int xv0 = ((fgrp)     ^ (frow & 7)) << 3;
  const int xv1 = ((4 + fgrp) ^ (frow & 7)) << 3;
  const int aB = wr * 8192 + frow * 64;
  const int bB = (wc >> 1) * 8192 + (wc & 1) * 4096 + frow * 64;

  f32x4 acc[8][4];
  #pragma unroll
  for (int i = 0; i < 8; ++i)
    #pragma unroll
    for (int j = 0; j < 4; ++j) acc[i][j] = (f32x4){0.f,0.f,0.f,0.f};
  s16x8 af[4][2], bfr[4][2];

  const int NT = K >> 6;       // K-tiles (BK=64); all Ks give NT even, >= 16
  const int NI = NT >> 1;

  // prologue: tile0 (4 halves) + tile1 (3 halves); vmcnt(6) -> tile0 landed
  STAGE(1,0,0,0); STAGE(1,0,1,0); STAGE(0,0,0,0); STAGE(0,0,1,0);
  STAGE(1,1,0,1); STAGE(1,1,1,1); STAGE(0,1,0,1);
  VM6(); BAR();

  for (int i = 0; i < NI; ++i){
    const int kt1  = 2*i + 1;
    const int kn0  = (2*i + 2 < NT) ? 2*i + 2 : NT - 2;  // slot0 refill (safe rewrite at tail)
    const int kn1  = (2*i + 3 < NT) ? 2*i + 3 : NT - 1;  // slot1 refill
    // ph0: read slot0 A rows0-3 + B; stage slot1.A1 <- kt1 (4th half of current slot1 tile)
    LOADA(0,0); LOADB(0);
    STAGE(0,1,1,kt1);
    BAR(); LGKM0();
    __builtin_amdgcn_s_setprio(1); MFMAQ(0,0); __builtin_amdgcn_s_setprio(0);
    BAR();
    // ph1: stage slot0.B0 <- kn0
    STAGE(1,0,0,kn0);
    BAR();
    __builtin_amdgcn_s_setprio(1); MFMAQ(0,1); __builtin_amdgcn_s_setprio(0);
    BAR();
    // ph2: read slot0 A rows4-7; stage slot0.B1
    LOADA(0,1);
    STAGE(1,0,1,kn0);
    BAR(); LGKM0();
    __builtin_amdgcn_s_setprio(1); MFMAQ(1,0); __builtin_amdgcn_s_setprio(0);
    BAR();
    // ph3: stage slot0.A0; vmcnt(6) -> slot1 tile fully landed for ph4
    STAGE(0,0,0,kn0);
    BAR();
    __builtin_amdgcn_s_setprio(1); MFMAQ(1,1); __builtin_amdgcn_s_setprio(0);
    VM6(); BAR();
    // ph4: read slot1 A rows0-3 + B; stage slot0.A1
    LOADA(1,0); LOADB(1);
    STAGE(0,0,1,kn0);
    BAR(); LGKM0();
    __builtin_amdgcn_s_setprio(1); MFMAQ(0,0); __builtin_amdgcn_s_setprio(0);
    BAR();
    // ph5: stage slot1.B0 <- kn1
    STAGE(1,1,0,kn1);
    BAR();
    __builtin_amdgcn_s_setprio(1); MFMAQ(0,1); __builtin_amdgcn_s_setprio(0);
    BAR();
    // ph6: read slot1 A rows4-7; stage slot1.B1
    LOADA(1,1);
    STAGE(1,1,1,kn1);
    BAR(); LGKM0();
    __builtin_amdgcn_s_setprio(1); MFMAQ(1,0); __builtin_amdgcn_s_setprio(0);
    BAR();
    // ph7: stage slot1.A0; vmcnt(6) -> slot0 tile fully landed for next ph0
    STAGE(0,1,0,kn1);
    BAR();
    __builtin_amdgcn_s_setprio(1); MFMAQ(1,1); __builtin_amdgcn_s_setprio(0);
    VM6(); BAR();
  }

  // epilogue: C/D layout col=lane&15, row=(lane>>4)*4+reg
  #pragma unroll
  for (int i2 = 0; i2 < 8; ++i2){
    #pragma unroll
    for (int j2 = 0; j2 < 4; ++j2){
      #pragma unroll
      for (int r = 0; r < 4; ++r){
        int lrow = row0 + wr*128 + i2*16 + fgrp*4 + r;
        int col  = col0 + wc*64 + j2*16 + frow;
        float v = acc[i2][j2][r];
        if (MODE == 0){
          int grow = r0 + lrow;
          v += bias_mat[(size_t)(grow >> 12)*N + col];
          v = fmaxf(v, 0.f);
          ((u16*)Cv)[(size_t)lrow*N + col] = f2bf(v);
        } else if (MODE == 1){
          int grow = r0 + lrow;
          v += bias_vec[col] + 0.1f*resid[(size_t)grow*1024 + col];
          ((u16*)Cv)[(size_t)lrow*N + col] = f2bf(v);
        } else if (MODE == 2){
          v += bias_vec[col];
          v = fmaxf(v, 0.f);
          ((u16*)Cv)[(size_t)lrow*N + col] = f2bf(v);
        } else {
          v += bias_vec[col];
          ((float*)Cv)[(size_t)lrow*N + col] = v;
        }
      }
    }
  }
}

extern "C" void kernel_launch(void* const* d_in, const int* in_sizes, int n_in,
                              void* d_out, int out_size, void* d_ws, size_t ws_size,
                              hipStream_t stream){
  const float* term = (const float*)d_in[0];
  const float* pred = (const float*)d_in[1];
  const float* W1   = (const float*)d_in[2];
  const float* b1   = (const float*)d_in[3];
  const float* W2   = (const float*)d_in[4];
  const float* b2   = (const float*)d_in[5];
  const float* M1   = (const float*)d_in[6];
  const float* mb1  = (const float*)d_in[7];
  const float* M2   = (const float*)d_in[8];
  const float* mb2  = (const float*)d_in[9];
  const int* head = (const int*)d_in[10];
  const int* tail = (const int*)d_in[11];
  const int* sign = (const int*)d_in[12];
  float* out = (float*)d_out;

  char* ws = (char*)d_ws;
  u16* W1T = (u16*)ws;  ws += (size_t)4096*2048*2;
  u16* W2T = (u16*)ws;  ws += (size_t)1024*4096*2;
  u16* M1T = (u16*)ws;  ws += (size_t)4096*1024*2;
  u16* M2T = (u16*)ws;  ws += (size_t)1024*4096*2;
  float* bias1 = (float*)ws; ws += (size_t)8*4096*4;
  size_t used = (size_t)(ws - (char*)d_ws);

  int R = 32768;  // rows per chunk (multiple of 256)
  while (R > 256 && used + (size_t)R*12288 > ws_size) R >>= 1;
  u16* bufA = (u16*)ws;                          // X1 chunk [R][2048], later x [R][1024]
  u16* bufB = (u16*)(ws + (size_t)R*2048*2);     // h1 chunk [R][4096], later h2

  transpose_f32_bf16<<<dim3(4096/32, 2048/32), 256, 0, stream>>>(W1, W1T, 2048, 4096);
  transpose_f32_bf16<<<dim3(1024/32, 4096/32), 256, 0, stream>>>(W2, W2T, 4096, 1024);
  transpose_f32_bf16<<<dim3(4096/32, 1024/32), 256, 0, stream>>>(M1, M1T, 1024, 4096);
  transpose_f32_bf16<<<dim3(1024/32, 4096/32), 256, 0, stream>>>(M2, M2T, 4096, 1024);
  build_bias1<<<dim3(8*4096/256), 256, 0, stream>>>(W1, b1, head, tail, sign, bias1);

  for (int r0 = 0; r0 < 32768; r0 += R){
    build_x1<<<dim3(R), 256, 0, stream>>>(term, pred, head, tail, bufA, r0);
    gemm256<0><<<dim3(4096/256, R/256), 512, 0, stream>>>(bufA, W1T, bufB, 4096, 2048, r0, bias1, nullptr, nullptr);
    gemm256<1><<<dim3(1024/256, R/256), 512, 0, stream>>>(bufB, W2T, bufA, 1024, 4096, r0, nullptr, b2, term);
    gemm256<2><<<dim3(4096/256, R/256), 512, 0, stream>>>(bufA, M1T, bufB, 4096, 1024, r0, nullptr, mb1, nullptr);
    gemm256<3><<<dim3(1024/256, R/256), 512, 0, stream>>>(bufB, M2T, out + (size_t)r0*1024, 1024, 4096, r0, nullptr, mb2, nullptr);
  }
}

// Round 4
// 1341.995 us; speedup vs baseline: 1.4056x; 1.0076x over previous
//
#include <hip/hip_runtime.h>
#include <hip/hip_bf16.h>
#include <cstdint>

typedef unsigned short u16;
typedef __attribute__((ext_vector_type(8))) u16 u16x8;
typedef __attribute__((ext_vector_type(8))) short s16x8;   // bf16 MFMA frag
typedef __attribute__((ext_vector_type(4))) float f32x4;

#define AS1(p) ((const __attribute__((address_space(1))) void*)(p))
#define AS3(p) ((__attribute__((address_space(3))) void*)(p))

__device__ __forceinline__ u16 f2bf(float f){
  union{float f; uint32_t i;} x; x.f = f;
  uint32_t r = x.i + 0x7fff + ((x.i>>16)&1);
  return (u16)(r>>16);
}

// ------------- weight transpose: in f32 [K][N] -> out bf16 [N][K] ------------
__global__ void transpose_f32_bf16(const float* __restrict__ in, u16* __restrict__ out,
                                   int K, int N){
  __shared__ u16 tile[32][33];
  const int tid = threadIdx.x;
  const int bx = blockIdx.x, by = blockIdx.y;
  const int xl = tid & 31, yl = tid >> 5;
  #pragma unroll
  for (int r = 0; r < 4; ++r){
    int y = by*32 + yl + r*8;
    tile[yl + r*8][xl] = f2bf(in[(size_t)y*N + bx*32 + xl]);
  }
  __syncthreads();
  #pragma unroll
  for (int r = 0; r < 4; ++r){
    int oy = bx*32 + yl + r*8;
    int ox = by*32 + xl;
    out[(size_t)oy*K + ox] = tile[xl][yl + r*8];
  }
}

// -------- bias1[t][h] = b1[h] + cH_t*W1[2048,h] + cS_t*W1[2049,h] (f32) ------
__global__ void build_bias1(const float* __restrict__ W1, const float* __restrict__ b1,
                            const int* __restrict__ head, const int* __restrict__ tail,
                            const int* __restrict__ sign, float* __restrict__ bias1){
  int idx = blockIdx.x*256 + threadIdx.x;
  int t = idx >> 12, h = idx & 4095;
  float cH = 0.f, cS = 0.f;
  #pragma unroll
  for (int e = 0; e < 16; ++e){
    float s = 1.f - 2.f*(float)sign[e];
    if (head[e] == t){ cH += 1.f; cS += s; }
    if (tail[e] == t){ cH -= 1.f; cS += s; }
  }
  bias1[idx] = b1[h] + cH*W1[(size_t)2048*4096 + h] + cS*W1[(size_t)2049*4096 + h];
}

// --- X1[r,0:1024] = bf16(deg_t*term[r]); X1[r,1024:2048] = bf16(sum pred) ----
__global__ void build_x1(const float* __restrict__ term, const float* __restrict__ pred,
                         const int* __restrict__ head, const int* __restrict__ tail,
                         u16* __restrict__ X1, int r0){
  int idx = blockIdx.x*256 + threadIdx.x;
  int lr = idx >> 8;
  int c8 = (idx & 255) * 8;
  int grow = r0 + lr;
  int t = grow >> 12;
  int b = grow & 4095;
  float v[8];
  if (c8 < 1024){
    int deg = 0;
    #pragma unroll
    for (int e = 0; e < 16; ++e) deg += (head[e]==t) + (tail[e]==t);
    float d = (float)deg;
    const float4* p = (const float4*)(term + (size_t)grow*1024 + c8);
    float4 lo = p[0], hi = p[1];
    v[0]=d*lo.x; v[1]=d*lo.y; v[2]=d*lo.z; v[3]=d*lo.w;
    v[4]=d*hi.x; v[5]=d*hi.y; v[6]=d*hi.z; v[7]=d*hi.w;
  } else {
    int f = c8 - 1024;
    #pragma unroll
    for (int j = 0; j < 8; ++j) v[j] = 0.f;
    #pragma unroll
    for (int e = 0; e < 16; ++e){
      int w = (head[e]==t) + (tail[e]==t);
      if (w){
        const float4* p = (const float4*)(pred + ((size_t)e<<22) + ((size_t)b<<10) + f);
        float4 lo = p[0], hi = p[1];
        float fw = (float)w;
        v[0]+=fw*lo.x; v[1]+=fw*lo.y; v[2]+=fw*lo.z; v[3]+=fw*lo.w;
        v[4]+=fw*hi.x; v[5]+=fw*hi.y; v[6]+=fw*hi.z; v[7]+=fw*hi.w;
      }
    }
  }
  u16x8 o;
  #pragma unroll
  for (int j = 0; j < 8; ++j) o[j] = f2bf(v[j]);
  *(u16x8*)(X1 + (size_t)lr*2048 + c8) = o;
}

// =====================  256x256 8-phase GEMM (T1+T2+T3+T4+T5)  ===============
// 512 thr = 8 waves (2Mx4N), per-wave 128x64 out, BK=64, LDS 128KB.
// ds_reads balanced 12/4/8/0 per K-tile (quadrant order (0,0),(0,1),(1,1),(1,0);
// A-frags reloaded at 3rd phase -> register-neutral). Stage order per iter:
//   ph0: s1.A0(kt1)  ph1: s1.A1(kt1)  ph2: s0.B0(kn0)  ph3: s0.B1(kn0)
//   ph4: s0.A0(kn0)  ph5: s0.A1(kn0)  ph6: s1.B0(kn1)  ph7: s1.B1(kn1)
// vmcnt(4) at ph3/ph7 ends: completes the 8 gloads of the slot read next,
// leaves 4 in flight (never drains to 0). WAR: every region staged >=1 barrier
// after its reads drain (verified per-region).
#define FENCE() asm volatile("" ::: "memory")
#define BAR()   do{ FENCE(); __builtin_amdgcn_s_barrier(); FENCE(); }while(0)
#define LGKM0() do{ asm volatile("s_waitcnt lgkmcnt(0)" ::: "memory"); \
                    __builtin_amdgcn_sched_barrier(0); }while(0)
#define LGKM8() asm volatile("s_waitcnt lgkmcnt(8)" ::: "memory")
#define VM4()   asm volatile("s_waitcnt vmcnt(4)" ::: "memory")

#define STAGE(isB, slot, half, kt) do{ \
    const u16* _s = (isB ? bStage : aStage) + ((half) ? halfStride : (size_t)0) + ((size_t)(kt) << 6); \
    u16* _d = &LDS[(isB ? 32768 : 0) + (slot)*16384 + (half)*8192 + tid*8]; \
    __builtin_amdgcn_global_load_lds(AS1(_s), AS3(_d), 16, 0, 0); \
    __builtin_amdgcn_global_load_lds(AS1(_s + q2s), AS3(_d + 4096), 16, 0, 0); \
  }while(0)

#define LOADA(slot, rh) do{ \
    _Pragma("unroll") \
    for (int ii = 0; ii < 4; ++ii){ \
      af[ii][0] = *(const s16x8*)&LDS[(slot)*16384 + aB + ((rh)*4+ii)*1024 + xv0]; \
      af[ii][1] = *(const s16x8*)&LDS[(slot)*16384 + aB + ((rh)*4+ii)*1024 + xv1]; \
    } }while(0)

#define LOADB01(slot) do{ \
    _Pragma("unroll") \
    for (int jj = 0; jj < 2; ++jj){ \
      bfr[jj][0] = *(const s16x8*)&LDS[32768 + (slot)*16384 + bB + jj*1024 + xv0]; \
      bfr[jj][1] = *(const s16x8*)&LDS[32768 + (slot)*16384 + bB + jj*1024 + xv1]; \
    } }while(0)

#define LOADB23(slot) do{ \
    _Pragma("unroll") \
    for (int jj = 2; jj < 4; ++jj){ \
      bfr[jj][0] = *(const s16x8*)&LDS[32768 + (slot)*16384 + bB + jj*1024 + xv0]; \
      bfr[jj][1] = *(const s16x8*)&LDS[32768 + (slot)*16384 + bB + jj*1024 + xv1]; \
    } }while(0)

#define MFMAQ(rh, ch) do{ \
    _Pragma("unroll") \
    for (int ii = 0; ii < 4; ++ii){ \
      _Pragma("unroll") \
      for (int jj = 0; jj < 2; ++jj){ \
        acc[(rh)*4+ii][(ch)*2+jj] = __builtin_amdgcn_mfma_f32_16x16x32_bf16(af[ii][0], bfr[(ch)*2+jj][0], acc[(rh)*4+ii][(ch)*2+jj], 0,0,0); \
        acc[(rh)*4+ii][(ch)*2+jj] = __builtin_amdgcn_mfma_f32_16x16x32_bf16(af[ii][1], bfr[(ch)*2+jj][1], acc[(rh)*4+ii][(ch)*2+jj], 0,0,0); \
      } } }while(0)

#define PRIO_MFMA(rh, ch) do{ \
    __builtin_amdgcn_s_setprio(1); MFMAQ(rh, ch); __builtin_amdgcn_s_setprio(0); }while(0)

template<int MODE>
__launch_bounds__(512, 2)
__global__ void gemm256(const u16* __restrict__ A, const u16* __restrict__ Bt,
                        void* __restrict__ Cv, int N, int K, int r0,
                        const float* __restrict__ bias_mat,
                        const float* __restrict__ bias_vec,
                        const float* __restrict__ resid){
  __shared__ u16 LDS[65536];   // 128 KiB
  const int tid = threadIdx.x;
  const int lane = tid & 63;
  const int wid = tid >> 6;
  const int wr = wid >> 2, wc = wid & 3;
  const int frow = lane & 15, fgrp = lane >> 4;

  // T1: bijective XCD swizzle
  int nwg = gridDim.x * gridDim.y;
  int orig = blockIdx.y * gridDim.x + blockIdx.x;
  int id = orig;
  if ((nwg & 7) == 0){ int cpx = nwg >> 3; id = (orig & 7) * cpx + (orig >> 3); }
  const int bx = id % gridDim.x, by = id / gridDim.x;
  const int row0 = by * 256, col0 = bx * 256;

  // stage source bases (pre-swizzled global source, linear LDS dest)
  const size_t rowK = (size_t)(tid >> 3) * K;
  const int sg8 = (((tid & 7) ^ ((tid >> 3) & 7)) << 3);
  const u16* aStage = A  + (size_t)row0 * K + rowK + sg8;
  const u16* bStage = Bt + (size_t)col0 * K + rowK + sg8;
  const size_t halfStride = (size_t)128 * K;
  const size_t q2s = (size_t)64 * K;

  // fragment read offsets (u16 units), swizzled
  const int xv0 = ((fgrp)     ^ (frow & 7)) << 3;
  const int xv1 = ((4 + fgrp) ^ (frow & 7)) << 3;
  const int aB = wr * 8192 + frow * 64;
  const int bB = (wc >> 1) * 8192 + (wc & 1) * 4096 + frow * 64;

  f32x4 acc[8][4];
  #pragma unroll
  for (int i = 0; i < 8; ++i)
    #pragma unroll
    for (int j = 0; j < 4; ++j) acc[i][j] = (f32x4){0.f,0.f,0.f,0.f};
  s16x8 af[4][2], bfr[4][2];

  const int NT = K >> 6;       // K-tiles (BK=64); NT even, >= 16 for all our Ks
  const int NI = NT >> 1;

  // prologue: slot0 <- tile0 (8 gloads, FIRST so vmcnt(4) covers them),
  // then slot1.B <- tile1 (4 gloads). slot1.A staged in-loop at ph0/ph1.
  STAGE(1,0,0,0); STAGE(1,0,1,0); STAGE(0,0,0,0); STAGE(0,0,1,0);
  STAGE(1,1,0,1); STAGE(1,1,1,1);
  VM4(); BAR();

  for (int i = 0; i < NI; ++i){
    const int kt1 = 2*i + 1;
    const int kn0 = (2*i + 2 < NT) ? 2*i + 2 : NT - 2;  // identical rewrite at tail
    const int kn1 = (2*i + 3 < NT) ? 2*i + 3 : NT - 1;
    // ph0: 12 ds_reads (A rows0-63 + B stripes01), stage s1.A0
    LOADA(0,0); LOADB01(0);
    STAGE(0,1,0,kt1);
    LGKM8();
    BAR(); LGKM0();
    PRIO_MFMA(0,0);
    BAR();
    // ph1: 4 ds_reads (B stripes23), stage s1.A1
    LOADB23(0);
    STAGE(0,1,1,kt1);
    BAR(); LGKM0();
    PRIO_MFMA(0,1);
    BAR();
    // ph2: 8 ds_reads (A rows64-127), stage s0.B0 (s0.B drained ph1)
    LOADA(0,1);
    STAGE(1,0,0,kn0);
    BAR(); LGKM0();
    PRIO_MFMA(1,1);
    BAR();
    // ph3: 0 ds_reads, stage s0.B1; vmcnt(4) -> s1 fully landed for ph4
    STAGE(1,0,1,kn0);
    BAR();
    PRIO_MFMA(1,0);
    VM4(); BAR();
    // ph4: 12 ds_reads (slot1), stage s0.A0 (s0.A drained ph2)
    LOADA(1,0); LOADB01(1);
    STAGE(0,0,0,kn0);
    LGKM8();
    BAR(); LGKM0();
    PRIO_MFMA(0,0);
    BAR();
    // ph5: 4 ds_reads, stage s0.A1
    LOADB23(1);
    STAGE(0,0,1,kn0);
    BAR(); LGKM0();
    PRIO_MFMA(0,1);
    BAR();
    // ph6: 8 ds_reads, stage s1.B0 (s1.B drained ph5)
    LOADA(1,1);
    STAGE(1,1,0,kn1);
    BAR(); LGKM0();
    PRIO_MFMA(1,1);
    BAR();
    // ph7: 0 ds_reads, stage s1.B1; vmcnt(4) -> s0 refill landed for next ph0
    STAGE(1,1,1,kn1);
    BAR();
    PRIO_MFMA(1,0);
    VM4(); BAR();
  }

  // epilogue: C/D layout col=lane&15, row=(lane>>4)*4+reg
  #pragma unroll
  for (int i2 = 0; i2 < 8; ++i2){
    #pragma unroll
    for (int j2 = 0; j2 < 4; ++j2){
      #pragma unroll
      for (int r = 0; r < 4; ++r){
        int lrow = row0 + wr*128 + i2*16 + fgrp*4 + r;
        int col  = col0 + wc*64 + j2*16 + frow;
        float v = acc[i2][j2][r];
        if (MODE == 0){
          int grow = r0 + lrow;
          v += bias_mat[(size_t)(grow >> 12)*N + col];
          v = fmaxf(v, 0.f);
          ((u16*)Cv)[(size_t)lrow*N + col] = f2bf(v);
        } else if (MODE == 1){
          int grow = r0 + lrow;
          v += bias_vec[col] + 0.1f*resid[(size_t)grow*1024 + col];
          ((u16*)Cv)[(size_t)lrow*N + col] = f2bf(v);
        } else if (MODE == 2){
          v += bias_vec[col];
          v = fmaxf(v, 0.f);
          ((u16*)Cv)[(size_t)lrow*N + col] = f2bf(v);
        } else {
          v += bias_vec[col];
          ((float*)Cv)[(size_t)lrow*N + col] = v;
        }
      }
    }
  }
}

extern "C" void kernel_launch(void* const* d_in, const int* in_sizes, int n_in,
                              void* d_out, int out_size, void* d_ws, size_t ws_size,
                              hipStream_t stream){
  const float* term = (const float*)d_in[0];
  const float* pred = (const float*)d_in[1];
  const float* W1   = (const float*)d_in[2];
  const float* b1   = (const float*)d_in[3];
  const float* W2   = (const float*)d_in[4];
  const float* b2   = (const float*)d_in[5];
  const float* M1   = (const float*)d_in[6];
  const float* mb1  = (const float*)d_in[7];
  const float* M2   = (const float*)d_in[8];
  const float* mb2  = (const float*)d_in[9];
  const int* head = (const int*)d_in[10];
  const int* tail = (const int*)d_in[11];
  const int* sign = (const int*)d_in[12];
  float* out = (float*)d_out;

  char* ws = (char*)d_ws;
  u16* W1T = (u16*)ws;  ws += (size_t)4096*2048*2;
  u16* W2T = (u16*)ws;  ws += (size_t)1024*4096*2;
  u16* M1T = (u16*)ws;  ws += (size_t)4096*1024*2;
  u16* M2T = (u16*)ws;  ws += (size_t)1024*4096*2;
  float* bias1 = (float*)ws; ws += (size_t)8*4096*4;
  size_t used = (size_t)(ws - (char*)d_ws);

  int R = 32768;  // rows per chunk (multiple of 256)
  while (R > 256 && used + (size_t)R*12288 > ws_size) R >>= 1;
  u16* bufA = (u16*)ws;
  u16* bufB = (u16*)(ws + (size_t)R*2048*2);

  transpose_f32_bf16<<<dim3(4096/32, 2048/32), 256, 0, stream>>>(W1, W1T, 2048, 4096);
  transpose_f32_bf16<<<dim3(1024/32, 4096/32), 256, 0, stream>>>(W2, W2T, 4096, 1024);
  transpose_f32_bf16<<<dim3(4096/32, 1024/32), 256, 0, stream>>>(M1, M1T, 1024, 4096);
  transpose_f32_bf16<<<dim3(1024/32, 4096/32), 256, 0, stream>>>(M2, M2T, 4096, 1024);
  build_bias1<<<dim3(8*4096/256), 256, 0, stream>>>(W1, b1, head, tail, sign, bias1);

  for (int r0 = 0; r0 < 32768; r0 += R){
    build_x1<<<dim3(R), 256, 0, stream>>>(term, pred, head, tail, bufA, r0);
    gemm256<0><<<dim3(4096/256, R/256), 512, 0, stream>>>(bufA, W1T, bufB, 4096, 2048, r0, bias1, nullptr, nullptr);
    gemm256<1><<<dim3(1024/256, R/256), 512, 0, stream>>>(bufB, W2T, bufA, 1024, 4096, r0, nullptr, b2, term);
    gemm256<2><<<dim3(4096/256, R/256), 512, 0, stream>>>(bufA, M1T, bufB, 4096, 1024, r0, nullptr, mb1, nullptr);
    gemm256<3><<<dim3(1024/256, R/256), 512, 0, stream>>>(bufB, M2T, out + (size_t)r0*1024, 1024, 4096, r0, nullptr, mb2, nullptr);
  }
}